// Round 6
// baseline (131.444 us; speedup 1.0000x reference)
//
#include <hip/hip_runtime.h>
#include <stdint.h>

typedef _Float16 half8 __attribute__((ext_vector_type(8)));
typedef float f32x16 __attribute__((ext_vector_type(16)));

// ---------------- layout ----------------
// th : theta^T fp16, [i(3)][f(64)][k(1728)], k = j*576 + c*18 + m
//      m<17: w_spline*cp[m] ; m==17: w_silu
// A  : built in-kernel per k-chunk of 144 (one j, one c-octet):
//      local k = c'*18 + m, c = oct*8 + c'. Dense rebuild: each thread owns
//      (px, c-pair) = 36 halves, computed in regs (same f32 formula as the
//      old prep: h_m = max(0,1-|u-m|), silu), stored as 9 aligned b64s.
//      No clears, no serial chain, uniform control flow.
#define NTH  (3 * 64 * 1728)             // 331776
#define PREP_BLOCKS (NTH / 256)          // 1296 exactly

__global__ __launch_bounds__(256) void kan_prep(
    const float* __restrict__ cp, const float* __restrict__ wspl,
    const float* __restrict__ wsil, _Float16* __restrict__ th)
{
    int e  = blockIdx.x * 256 + threadIdx.x;   // < NTH exactly
    int k  = e % 1728;
    int fi = e / 1728;
    int f  = fi & 63;
    int i  = fi >> 6;
    int j  = k / 576;
    int q  = k - j * 576;
    int c  = q / 18;
    int m  = q - c * 18;
    int base = ((f * 32 + c) * 3 + i) * 3 + j;           // (F,C,3,3) flat
    float v = (m < 17) ? wspl[base] * cp[base * 17 + m] : wsil[base];
    th[e] = (_Float16)v;
}

// Fused GEMM, ATOMIC-FREE: block = 256 thr = 4 waves (2 px x 2 f halves),
// tile 64 px x 64 f, FULL K = 3*1728 = 5184 in 36 chunks of 144
// (i = ch/12, j = (ch%12)>>2, oct = ch&3). One block per output row
// => plain stores, no memset, out written exactly once.
// Grid 256 = 1 block/CU, zero tail. LDS rows 152 halves (304 B);
// A pad halves 144..151 never read. Single buffer, 2 barriers/chunk,
// reg-prefetch B (5x uint4) + x (float2) one chunk ahead.
__global__ __launch_bounds__(256) void kan_main(
    const float* __restrict__ x, const _Float16* __restrict__ th,
    const float* __restrict__ bias, float* __restrict__ out)
{
    __shared__ __align__(16) _Float16 lA[64 * 152];    // 19456 B
    __shared__ __align__(16) _Float16 lB[64 * 152];    // 19456 B

    const int bx = blockIdx.x;                     // 0..255
    const int b  = bx >> 6;
    const int ho = bx & 63;

    const int tid  = threadIdx.x;                  // 0..255
    const int wv   = tid >> 6;
    const int wpx  = wv >> 1;                      // px half
    const int wf   = wv & 1;                       // f half
    const int lane = tid & 63;
    const int r31  = lane & 31;
    const int kh   = lane >> 5;

    // ---- B staging map: 64 rows x 288 B = 1152 16B-units; unit id = tid+256r
    int goffB[5], doffB[5];
#pragma unroll
    for (int r = 0; r < 5; ++r) {
        int id  = tid + 256 * r;
        int row = id / 18;
        int u   = id - row * 18;
        goffB[r] = row * 3456 + u * 16;            // + i*221184 + j*1152 + oct*288
        doffB[r] = row * 304 + u * 16;
    }
    const char* thB = (const char*)th;

    // ---- A map: thread owns (px = tid>>2, c-pair cc = tid&3)
    const int apx = tid >> 2;
    const int cc  = tid & 3;
    // x float base for (b, ho + i, w = apx + j, c): offset i*2112 + j*32 + ...
    const float* xb = x + ((size_t)((b * 66 + ho) * 66 + apx)) * 32;
    char* aBase = (char*)lA + apx * 304 + cc * 72; // 36-half cell [d0:18|d1:18]

    // ---- prefetch chunk 0 (i=0, j=0, oct=0)
    uint4 bPF[5];
    float2 xPF;
#pragma unroll
    for (int r = 0; r < 5; ++r)
        if (r < 4 || tid < 128)
            bPF[r] = *(const uint4*)(thB + goffB[r]);
    xPF = *(const float2*)(xb + cc * 2);

    f32x16 acc;
    {
        float bv = bias[wf * 32 + r31];
#pragma unroll
        for (int r = 0; r < 16; ++r) acc[r] = bv;
    }

    const _Float16* pa = lA + (wpx * 32 + r31) * 152 + kh * 8;
    const _Float16* pb = lB + (wf  * 32 + r31) * 152 + kh * 8;

    for (int ch = 0; ch < 36; ++ch) {
        // ---- stage B (consume prefetch regs)
#pragma unroll
        for (int r = 0; r < 5; ++r)
            if (r < 4 || tid < 128)
                *(uint4*)((char*)lB + doffB[r]) = bPF[r];
        // ---- build A cell densely in regs, store 9 aligned b64s
        {
            union { _Float16 h[36]; uint64_t q[9]; } pk;
            float p0 = xPF.x, p1 = xPF.y;
            float u0 = fmaf(fminf(1.0f, fmaxf(-1.0f, p0)), 8.0f, 8.0f);
            float u1 = fmaf(fminf(1.0f, fmaxf(-1.0f, p1)), 8.0f, 8.0f);
#pragma unroll
            for (int m = 0; m < 17; ++m) {
                pk.h[m]      = (_Float16)fmaxf(0.0f, 1.0f - fabsf(u0 - (float)m));
                pk.h[18 + m] = (_Float16)fmaxf(0.0f, 1.0f - fabsf(u1 - (float)m));
            }
            pk.h[17] = (_Float16)(p0 * __builtin_amdgcn_rcpf(1.0f + __expf(-p0)));
            pk.h[35] = (_Float16)(p1 * __builtin_amdgcn_rcpf(1.0f + __expf(-p1)));
            uint64_t* dst = (uint64_t*)aBase;      // 8-aligned (304,72 % 8 == 0)
#pragma unroll
            for (int r = 0; r < 9; ++r) dst[r] = pk.q[r];
        }
        // ---- prefetch chunk ch+1
        if (ch < 35) {
            int n  = ch + 1;
            int i2 = n / 12;
            int rr = n - i2 * 12;
            int j2 = rr >> 2, o2 = rr & 3;
            const char* tb = thB + i2 * 221184 + j2 * 1152 + o2 * 288;
#pragma unroll
            for (int r = 0; r < 5; ++r)
                if (r < 4 || tid < 128)
                    bPF[r] = *(const uint4*)(tb + goffB[r]);
            xPF = *(const float2*)(xb + i2 * 2112 + j2 * 32 + o2 * 8 + cc * 2);
        }
        __syncthreads();                           // A, B ready
#pragma unroll
        for (int s = 0; s < 9; ++s) {
            half8 a  = *(const half8*)(pa + s * 16);
            half8 bf = *(const half8*)(pb + s * 16);
            acc = __builtin_amdgcn_mfma_f32_32x32x16_f16(a, bf, acc, 0, 0, 0);
        }
        if (ch < 35) __syncthreads();              // readers done
    }

    // C/D layout (verified): col = lane&31, row = (reg&3)+8*(reg>>2)+4*(lane>>5)
    float* obase = out
        + ((size_t)((b * 64 + ho) * 64 + wpx * 32)) * 64 + wf * 32;
#pragma unroll
    for (int r = 0; r < 16; ++r) {
        int rowD = (r & 3) + 8 * (r >> 2) + 4 * kh;  // px within the 32-block
        obase[(size_t)rowD * 64 + r31] = acc[r];     // plain store, no atomics
    }
}

extern "C" void kernel_launch(void* const* d_in, const int* in_sizes, int n_in,
                              void* d_out, int out_size, void* d_ws, size_t ws_size,
                              hipStream_t stream) {
    const float* x    = (const float*)d_in[0];
    const float* cp   = (const float*)d_in[1];
    const float* wspl = (const float*)d_in[2];
    const float* wsil = (const float*)d_in[3];
    const float* bias = (const float*)d_in[4];
    float* out = (float*)d_out;

    _Float16* th = (_Float16*)d_ws;

    kan_prep<<<PREP_BLOCKS, 256, 0, stream>>>(cp, wspl, wsil, th);
    kan_main<<<256, 256, 0, stream>>>(x, th, bias, out);
}

// Round 7
// 120.676 us; speedup vs baseline: 1.0892x; 1.0892x over previous
//
#include <hip/hip_runtime.h>
#include <stdint.h>

typedef _Float16 half8 __attribute__((ext_vector_type(8)));
typedef float f32x16 __attribute__((ext_vector_type(16)));
typedef float f32x4  __attribute__((ext_vector_type(4)));

// ---------------- layout ----------------
// th : theta^T fp16, [i(3)][f(64)][k(1728)], k = j*576 + c*18 + m
//      m<17: w_spline*cp[m] ; m==17: w_silu
// A' : LDS, per i: [pixel w 0..65][k' = c*18 + m, 576 used, pad to 584]
//      built from x once per i, read by all three j (row shift +j).
// B  : LDS, per (i,j): [f 0..63][k' 0..575, pad to 584]
// Row stride 584 halves = 1168 B = 292 dw == 4 (mod 32): the measured
// zero-conflict pattern (R2/R4: 144B==4 -> 0 conflicts; R5/R6: 304B==12
// -> 1.3-1.8M conflicts).
#define NTH  (3 * 64 * 1728)             // 331776
#define PREP_BLOCKS (NTH / 256)          // 1296 exactly

__global__ __launch_bounds__(256) void kan_prep(
    const float* __restrict__ cp, const float* __restrict__ wspl,
    const float* __restrict__ wsil, _Float16* __restrict__ th)
{
    int e  = blockIdx.x * 256 + threadIdx.x;   // < NTH exactly
    int k  = e % 1728;
    int fi = e / 1728;
    int f  = fi & 63;
    int i  = fi >> 6;
    int j  = k / 576;
    int q  = k - j * 576;
    int c  = q / 18;
    int m  = q - c * 18;
    int base = ((f * 32 + c) * 3 + i) * 3 + j;           // (F,C,3,3) flat
    float v = (m < 17) ? wspl[base] * cp[base * 17 + m] : wsil[base];
    th[e] = (_Float16)v;
}

// Fused GEMM, atomic-free, 9 fat phases. Block = 256 thr = 4 waves
// (2 px-halves x 2 f-halves), tile 64px x 64f, grid 256 (one block per
// output row). Phase p: i = p/3, j = p%3, K-chunk 576, 36 MFMA/wave.
// RAW barriers (__builtin_amdgcn_s_barrier) + asm lgkmcnt(0) ONLY:
// no vmcnt(0) drain, so the 18-uint4 B prefetch issued in phase p stays
// in flight across both barriers and lands at phase p+1's ds_writes
// (the asm "memory" clobbers also pin the issue point in program order).
// x is fully register-cached at start: no stray global loads mid-loop.
__global__ __launch_bounds__(256, 1) void kan_main(
    const float* __restrict__ x, const _Float16* __restrict__ th,
    const float* __restrict__ bias, float* __restrict__ out)
{
    __shared__ __align__(16) _Float16 lA[66 * 584];    // 77088 B
    __shared__ __align__(16) _Float16 lB[64 * 584];    // 74752 B

    const int bx = blockIdx.x;                     // 0..255
    const int b  = bx >> 6;
    const int ho = bx & 63;

    const int tid  = threadIdx.x;                  // 0..255
    const int wv   = tid >> 6;
    const int wpx  = wv >> 1;                      // px half
    const int wf   = wv & 1;                       // f half
    const int lane = tid & 63;
    const int r31  = lane & 31;
    const int kh   = lane >> 5;

    // ---- B staging map: row f = tid>>2, 4 thr/row, 18 units16 each
    const int srow = tid >> 2;                     // 0..63 (also A' px)
    const int sc   = tid & 3;
    const _Float16* gB0 = th + (size_t)srow * 1728 + sc * 8;  // +i*110592+j*576+r*32
    char* dB0 = (char*)lB + srow * 1168 + sc * 16;            // +r*64

    // ---- x register cache: thread owns (px = tid>>2, c-octet = tid&3);
    //      tid<64 additionally own one cell of pixel rows 64/65.
    const int oct  = tid & 3;
    const int erow = 64 + (tid >> 5);
    const int ec   = tid & 31;
    f32x4 xm[3][2];
    float xe[3];
#pragma unroll
    for (int i = 0; i < 3; ++i) {
        const float* xr = x + ((size_t)((b * 66 + ho + i) * 66 + srow)) * 32 + oct * 8;
        xm[i][0] = *(const f32x4*)(xr);
        xm[i][1] = *(const f32x4*)(xr + 4);
        xe[i] = (tid < 64)
            ? x[((size_t)((b * 66 + ho + i) * 66 + erow)) * 32 + ec] : 0.0f;
    }

    // ---- prefetch phase-0 B into regs
    uint4 bPF[18];
#pragma unroll
    for (int r = 0; r < 18; ++r)
        bPF[r] = *(const uint4*)((const char*)gB0 + r * 64);

    f32x16 acc;
    {
        float bv = bias[wf * 32 + r31];
#pragma unroll
        for (int r = 0; r < 16; ++r) acc[r] = bv;
    }

    const _Float16* pb = lB + (wf * 32 + r31) * 584 + kh * 8;

#pragma unroll
    for (int p = 0; p < 9; ++p) {
        const int i = p / 3, j = p % 3;            // compile-time (unrolled)

        // ---- stage B from prefetch regs (18 ds_write_b128; compiler
        //      inserts the vmcnt wait for bPF here -- hidden under the
        //      previous phase's 36-MFMA compute)
#pragma unroll
        for (int r = 0; r < 18; ++r)
            *(uint4*)(dB0 + r * 64) = bPF[r];

        // ---- rebuild A' on new i (j==0): 8 cells (px, c=oct*8..+7)
        if (j == 0) {
            char* abase = (char*)lA + srow * 1168 + oct * 288;
#pragma unroll
            for (int np = 0; np < 4; ++np) {       // cell pairs -> 72B, 9 b64
                union { _Float16 h[36]; uint64_t q[9]; } pk;
#pragma unroll
                for (int d = 0; d < 2; ++d) {
                    const int n = np * 2 + d;      // c = oct*8 + n
                    float pv = xm[i][n >> 2][n & 3];
                    float u  = fmaf(fminf(1.0f, fmaxf(-1.0f, pv)), 8.0f, 8.0f);
#pragma unroll
                    for (int m = 0; m < 17; ++m)
                        pk.h[d * 18 + m] =
                            (_Float16)fmaxf(0.0f, 1.0f - fabsf(u - (float)m));
                    pk.h[d * 18 + 17] =
                        (_Float16)(pv * __builtin_amdgcn_rcpf(1.0f + __expf(-pv)));
                }
                uint64_t* dst = (uint64_t*)(abase + np * 72);  // 8-aligned
#pragma unroll
                for (int r = 0; r < 9; ++r) dst[r] = pk.q[r];
            }
            if (tid < 64) {                        // pixel rows 64,65
                union { _Float16 h[18]; uint32_t w[9]; } ew;
                float pv = xe[i];
                float u  = fmaf(fminf(1.0f, fmaxf(-1.0f, pv)), 8.0f, 8.0f);
#pragma unroll
                for (int m = 0; m < 17; ++m)
                    ew.h[m] = (_Float16)fmaxf(0.0f, 1.0f - fabsf(u - (float)m));
                ew.h[17] =
                    (_Float16)(pv * __builtin_amdgcn_rcpf(1.0f + __expf(-pv)));
                uint32_t* dst = (uint32_t*)((char*)lA + erow * 1168 + ec * 36);
#pragma unroll
                for (int r = 0; r < 9; ++r) dst[r] = ew.w[r];  // 4-aligned b32
            }
        }

        // ---- issue next phase's B prefetch (flies across the barriers)
        if (p < 8) {
            const int i2 = (p + 1) / 3, j2 = (p + 1) % 3;
            const _Float16* g = gB0 + i2 * 110592 + j2 * 576;
#pragma unroll
            for (int r = 0; r < 18; ++r)
                bPF[r] = *(const uint4*)((const char*)g + r * 64);
        }

        asm volatile("s_waitcnt lgkmcnt(0)" ::: "memory");  // my ds_writes done
        __builtin_amdgcn_s_barrier();                       // all staged
        __builtin_amdgcn_sched_barrier(0);

        // ---- 36 MFMA k-steps over this (i,j)
        const _Float16* pa = lA + (wpx * 32 + r31 + j) * 584 + kh * 8;
#pragma unroll
        for (int s = 0; s < 36; ++s) {
            half8 a  = *(const half8*)(pa + s * 16);
            half8 bf = *(const half8*)(pb + s * 16);
            acc = __builtin_amdgcn_mfma_f32_32x32x16_f16(a, bf, acc, 0, 0, 0);
        }

        asm volatile("s_waitcnt lgkmcnt(0)" ::: "memory");  // my reads retired
        __builtin_amdgcn_s_barrier();                       // safe to restage
    }

    // C/D layout (verified): col = lane&31, row = (reg&3)+8*(reg>>2)+4*(lane>>5)
    float* obase = out
        + ((size_t)((b * 64 + ho) * 64 + wpx * 32)) * 64 + wf * 32;
#pragma unroll
    for (int r = 0; r < 16; ++r) {
        int rowD = (r & 3) + 8 * (r >> 2) + 4 * kh;  // px within the 32-block
        obase[(size_t)rowD * 64 + r31] = acc[r];     // plain store, no atomics
    }
}

extern "C" void kernel_launch(void* const* d_in, const int* in_sizes, int n_in,
                              void* d_out, int out_size, void* d_ws, size_t ws_size,
                              hipStream_t stream) {
    const float* x    = (const float*)d_in[0];
    const float* cp   = (const float*)d_in[1];
    const float* wspl = (const float*)d_in[2];
    const float* wsil = (const float*)d_in[3];
    const float* bias = (const float*)d_in[4];
    float* out = (float*)d_out;

    _Float16* th = (_Float16*)d_ws;

    kan_prep<<<PREP_BLOCKS, 256, 0, stream>>>(cp, wspl, wsil, th);
    kan_main<<<256, 256, 0, stream>>>(x, th, bias, out);
}

// Round 8
// 88.438 us; speedup vs baseline: 1.4863x; 1.3645x over previous
//
#include <hip/hip_runtime.h>
#include <stdint.h>

typedef _Float16 half8 __attribute__((ext_vector_type(8)));
typedef float f32x16 __attribute__((ext_vector_type(16)));
typedef float f32x4  __attribute__((ext_vector_type(4)));

// ---------------- layout ----------------
// th2 (ws): PRE-IMAGE of the LDS B tile, 18 blobs (p = i*6 + j*2 + h2) of
//   37888 B each: rows f=0..63, row stride 296 halves (288 data + 8 pad
//   zeros); data kk=h2*288+cb -> theta[i][f][j*576 + kk], kk = c*18+m.
//   Linear blob == linear LDS image => global_load_lds (uniform LDS base +
//   lane*16) stages it with ZERO staging registers (R7's 18xuint4 prefetch
//   spilled to scratch: WRITE_SIZE 131.7 MB ~= 288 B/thr/phase).
// A' (LDS): per i: [px w 0..65][k' = c*18+m, 576 used, stride 584 halves].
//   Row strides 1168 B / 592 B are == 4 (mod 32) dwords: measured
//   conflict-free class for the b128 fragment reads (R2/R4: 0 conflicts).
#define NTH2 340992                       // halves: 18 * 18944
#define PREP_BLOCKS (NTH2 / 256)          // 1332 exactly

__global__ __launch_bounds__(256) void kan_prep(
    const float* __restrict__ cp, const float* __restrict__ wspl,
    const float* __restrict__ wsil, _Float16* __restrict__ th2)
{
    int e  = blockIdx.x * 256 + threadIdx.x;   // < NTH2 exactly
    int p  = e / 18944;
    int r  = e - p * 18944;
    int f  = r / 296;
    int cb = r - f * 296;
    int i  = p / 6;
    int jh = p - i * 6;
    int j  = jh >> 1;
    int h2 = jh & 1;
    float v = 0.0f;
    if (cb < 288) {
        int kk = h2 * 288 + cb;
        int c  = kk / 18;
        int m  = kk - c * 18;
        int base = ((f * 32 + c) * 3 + i) * 3 + j;       // (F,C,3,3) flat
        v = (m < 17) ? wspl[base] * cp[base * 17 + m] : wsil[base];
    }
    th2[e] = (_Float16)v;
}

// Fused GEMM, atomic-free. Block = 256 thr = 4 waves (2 px x 2 f halves),
// tile 64px x 64f, grid 256 (one block/output-row, 1 block/CU).
// 18 phases: i = p/6 (A' rebuilt per i), (j,h2) = phase, K-chunk 288,
// 18 MFMA/wave/phase. B double-buffered; phase p issues global_load_lds
// for p+1 (10 insts wave0, 9 waves1-3), then waits COUNTED vmcnt(10/9):
// p's loads (issued last phase) are drained, p+1's stay in flight across
// both barriers. No staging registers at all -> nothing to spill.
__global__ __launch_bounds__(256, 1) void kan_main(
    const float* __restrict__ x, const _Float16* __restrict__ th2,
    const float* __restrict__ bias, float* __restrict__ out)
{
    __shared__ __align__(16) _Float16 lA[66 * 584];      // 77088 B
    __shared__ __align__(16) _Float16 lB[2][64 * 296];   // 2 x 37888 B

    const int bx = blockIdx.x;                     // 0..255
    const int b  = bx >> 6;
    const int ho = bx & 63;

    const int tid  = threadIdx.x;                  // 0..255
    const int wv   = tid >> 6;
    const int wpx  = wv >> 1;                      // px half
    const int wf   = wv & 1;                       // f half
    const int lane = tid & 63;
    const int r31  = lane & 31;
    const int kh   = lane >> 5;

    const int srow = tid >> 2;                     // A' px row 0..63
    const int oct  = tid & 3;                      // c-octet
    const int erow = 64 + (tid >> 5);              // extra px rows (tid<64)
    const int ec   = tid & 31;

    const char* thB = (const char*)th2;

    // stage blob bi into LDS buffer lp: 37 units of 1024 B, unit u -> wave u&3
#define STAGE(lp, bi)                                                          \
    {                                                                          \
        const char* gs = thB + (size_t)(bi) * 37888 + lane * 16;               \
        char* ls = (char*)(lp);                                                \
        _Pragma("unroll")                                                      \
        for (int t = 0; t < 10; ++t) {                                         \
            int u = wv + 4 * t;                                                \
            if (u < 37)                                                        \
                __builtin_amdgcn_global_load_lds(                              \
                    (const __attribute__((address_space(1))) void*)(gs + u * 1024), \
                    (__attribute__((address_space(3))) void*)(ls + u * 1024),  \
                    16, 0, 0);                                                 \
        }                                                                      \
    }

    STAGE(lB[0], 0)                                // prologue: blob 0 in flight

    f32x16 acc;
    {
        float bv = bias[wf * 32 + r31];
#pragma unroll
        for (int r = 0; r < 16; ++r) acc[r] = bv;
    }

    for (int i = 0; i < 3; ++i) {
        // ---- x for this i (issued BEFORE this phase's STAGE so the A-build's
        //      consumption-wait does not drain the staged loads)
        const float* xr =
            x + ((size_t)((b * 66 + ho + i) * 66 + srow)) * 32 + oct * 8;
        f32x4 x0 = *(const f32x4*)(xr);
        f32x4 x1 = *(const f32x4*)(xr + 4);
        float xev = (tid < 64)
            ? x[((size_t)((b * 66 + ho + i) * 66 + erow)) * 32 + ec] : 0.0f;

#pragma unroll
        for (int q = 0; q < 6; ++q) {
            const int J  = q >> 1;                 // compile-time
            const int H2 = q & 1;
            const bool last = (q == 5) && (i == 2);

            // ---- (a) issue next blob's loads into the other buffer
            if (q < 5) { STAGE(lB[(q + 1) & 1], i * 6 + q + 1) }
            else if (i < 2) { STAGE(lB[0], (i + 1) * 6) }

            // ---- (b) rebuild A' on new i (consumes x regs; in-order vmcnt
            //      wait drains only x + already-needed blob loads)
            if (q == 0) {
                char* abase = (char*)lA + srow * 1168 + oct * 288;
#pragma unroll
                for (int np = 0; np < 4; ++np) {   // 2 cells -> 72 B, 9 b64
                    union { _Float16 h[36]; uint64_t qq[9]; } pk;
#pragma unroll
                    for (int d = 0; d < 2; ++d) {
                        const int n = np * 2 + d;  // c = oct*8 + n
                        float pv = (n < 4) ? x0[n] : x1[n - 4];
                        float u  = fmaf(fminf(1.0f, fmaxf(-1.0f, pv)), 8.0f, 8.0f);
#pragma unroll
                        for (int m = 0; m < 17; ++m)
                            pk.h[d * 18 + m] =
                                (_Float16)fmaxf(0.0f, 1.0f - fabsf(u - (float)m));
                        pk.h[d * 18 + 17] = (_Float16)(
                            pv * __builtin_amdgcn_rcpf(1.0f + __expf(-pv)));
                    }
                    uint64_t* dst = (uint64_t*)(abase + np * 72);
#pragma unroll
                    for (int r = 0; r < 9; ++r) dst[r] = pk.qq[r];
                }
                if (tid < 64) {                    // px rows 64, 65
                    union { _Float16 h[18]; uint32_t w[9]; } ew;
                    float pv = xev;
                    float u  = fmaf(fminf(1.0f, fmaxf(-1.0f, pv)), 8.0f, 8.0f);
#pragma unroll
                    for (int m = 0; m < 17; ++m)
                        ew.h[m] = (_Float16)fmaxf(0.0f, 1.0f - fabsf(u - (float)m));
                    ew.h[17] = (_Float16)(
                        pv * __builtin_amdgcn_rcpf(1.0f + __expf(-pv)));
                    uint32_t* dst = (uint32_t*)((char*)lA + erow * 1168 + ec * 36);
#pragma unroll
                    for (int r = 0; r < 9; ++r) dst[r] = ew.w[r];
                }
            }

            // ---- (c) counted wait: drain THIS phase's blob, keep next's in
            //      flight; lgkmcnt(0) publishes A ds_writes
            if (last)            asm volatile("s_waitcnt vmcnt(0) lgkmcnt(0)" ::: "memory");
            else if (wv == 0)    asm volatile("s_waitcnt vmcnt(10) lgkmcnt(0)" ::: "memory");
            else                 asm volatile("s_waitcnt vmcnt(9) lgkmcnt(0)" ::: "memory");
            __builtin_amdgcn_s_barrier();          // (d) staged + A visible
            __builtin_amdgcn_sched_barrier(0);

            // ---- (e) 18 MFMA k-steps over this (i, J, H2)
            const _Float16* pa =
                lA + (wpx * 32 + r31 + J) * 584 + H2 * 288 + kh * 8;
            const _Float16* pb = lB[q & 1] + (wf * 32 + r31) * 296 + kh * 8;
#pragma unroll
            for (int s = 0; s < 18; ++s) {
                half8 a  = *(const half8*)(pa + s * 16);
                half8 bf = *(const half8*)(pb + s * 16);
                acc = __builtin_amdgcn_mfma_f32_32x32x16_f16(a, bf, acc, 0, 0, 0);
            }

            // ---- (f) reads retired before anyone overwrites this buffer / A
            asm volatile("s_waitcnt lgkmcnt(0)" ::: "memory");
            __builtin_amdgcn_s_barrier();
        }
    }
#undef STAGE

    // C/D layout (verified): col = lane&31, row = (reg&3)+8*(reg>>2)+4*(lane>>5)
    float* obase = out
        + ((size_t)((b * 64 + ho) * 64 + wpx * 32)) * 64 + wf * 32;
#pragma unroll
    for (int r = 0; r < 16; ++r) {
        int rowD = (r & 3) + 8 * (r >> 2) + 4 * kh;  // px within the 32-block
        obase[(size_t)rowD * 64 + r31] = acc[r];     // plain store
    }
}

extern "C" void kernel_launch(void* const* d_in, const int* in_sizes, int n_in,
                              void* d_out, int out_size, void* d_ws, size_t ws_size,
                              hipStream_t stream) {
    const float* x    = (const float*)d_in[0];
    const float* cp   = (const float*)d_in[1];
    const float* wspl = (const float*)d_in[2];
    const float* wsil = (const float*)d_in[3];
    const float* bias = (const float*)d_in[4];
    float* out = (float*)d_out;

    _Float16* th2 = (_Float16*)d_ws;

    kan_prep<<<PREP_BLOCKS, 256, 0, stream>>>(cp, wspl, wsil, th2);
    kan_main<<<256, 256, 0, stream>>>(x, th2, bias, out);
}